// Round 13
// baseline (714.287 us; speedup 1.0000x reference)
//
#include <hip/hip_runtime.h>
#include <hip/hip_bf16.h>

#define NB 8
#define NS 1024
#define ND 1024
#define NH 16
#define NDK 64
#define NDFF 4096

typedef __bf16 bf16;
typedef __attribute__((ext_vector_type(8))) __bf16 bf16x8;
typedef __attribute__((ext_vector_type(4))) __bf16 bf16x4;
typedef __attribute__((ext_vector_type(4))) float f32x4;

__device__ __forceinline__ void gload16(const bf16* g, bf16* l) {
  __builtin_amdgcn_global_load_lds(
      (const __attribute__((address_space(1))) void*)g,
      (__attribute__((address_space(3))) void*)l, 16, 0, 0);
}

// ---- weight convert + transpose: W f32 [K][N] -> WT bf16 [N][K] ----
__global__ void wconv_t(const float* __restrict__ W, bf16* __restrict__ WT,
                        int K, int N) {
  __shared__ float tile[32][33];
  int n0 = blockIdx.x * 32, k0 = blockIdx.y * 32;
  int tx = threadIdx.x, ty = threadIdx.y;
#pragma unroll
  for (int i2 = 0; i2 < 4; ++i2) {
    int i = ty + i2 * 8;
    tile[i][tx] = W[(long)(k0 + i) * N + n0 + tx];
  }
  __syncthreads();
#pragma unroll
  for (int i2 = 0; i2 < 4; ++i2) {
    int i = ty + i2 * 8;
    WT[(long)(n0 + i) * K + k0 + tx] = (bf16)tile[tx][i];
  }
}

// ---- fused 8x square (1024x1024) weight convert in one launch ----
struct WPtrs { const float* w[8]; };
__global__ void wconv8(WPtrs wp, bf16* __restrict__ dst) {
  __shared__ float tile[32][33];
  int n0 = blockIdx.x * 32, k0 = blockIdx.y * 32;
  const float* W = wp.w[blockIdx.z];
  bf16* WT = dst + (size_t)blockIdx.z * (1024 * 1024);
  int tx = threadIdx.x, ty = threadIdx.y;
#pragma unroll
  for (int i2 = 0; i2 < 4; ++i2) {
    int i = ty + i2 * 8;
    tile[i][tx] = W[(long)(k0 + i) * 1024 + n0 + tx];
  }
  __syncthreads();
#pragma unroll
  for (int i2 = 0; i2 < 4; ++i2) {
    int i = ty + i2 * 8;
    WT[(long)(n0 + i) * 1024 + k0 + tx] = (bf16)tile[tx][i];
  }
}

// ---- fused layernorm: out_ln = bf16(LN(x)), out_lnpos = bf16(LN(x)+pos) ----
__global__ void ln_fused(const float* __restrict__ in, const float* __restrict__ gam,
                         const float* __restrict__ bet, const float* __restrict__ pos,
                         bf16* __restrict__ out_ln, bf16* __restrict__ out_lnpos) {
  long row = blockIdx.x;
  int t = threadIdx.x;  // 256
  float4 v = ((const float4*)(in + row * ND))[t];
  float s = v.x + v.y + v.z + v.w;
  float s2 = v.x * v.x + v.y * v.y + v.z * v.z + v.w * v.w;
#pragma unroll
  for (int m = 32; m >= 1; m >>= 1) {
    s += __shfl_xor(s, m);
    s2 += __shfl_xor(s2, m);
  }
  __shared__ float red[8];
  if ((t & 63) == 0) {
    red[t >> 6] = s;
    red[4 + (t >> 6)] = s2;
  }
  __syncthreads();
  float ts = red[0] + red[1] + red[2] + red[3];
  float ts2 = red[4] + red[5] + red[6] + red[7];
  float mu = ts * (1.0f / ND);
  float var = ts2 * (1.0f / ND) - mu * mu;
  float rstd = rsqrtf(var + 1e-5f);
  float4 g4 = ((const float4*)gam)[t];
  float4 b4 = ((const float4*)bet)[t];
  float o0 = (v.x - mu) * rstd * g4.x + b4.x;
  float o1 = (v.y - mu) * rstd * g4.y + b4.y;
  float o2 = (v.z - mu) * rstd * g4.z + b4.z;
  float o3 = (v.w - mu) * rstd * g4.w + b4.w;
  if (out_ln) {
    bf16x4 q;
    q[0] = (bf16)o0; q[1] = (bf16)o1; q[2] = (bf16)o2; q[3] = (bf16)o3;
    *(bf16x4*)(out_ln + row * ND + t * 4) = q;
  }
  if (out_lnpos) {
    float4 p4 = ((const float4*)(pos + row * ND))[t];
    bf16x4 q;
    q[0] = (bf16)(o0 + p4.x); q[1] = (bf16)(o1 + p4.y);
    q[2] = (bf16)(o2 + p4.z); q[3] = (bf16)(o3 + p4.w);
    *(bf16x4*)(out_lnpos + row * ND + t * 4) = q;
  }
}

// ---- GEMM v6s: concurrency-max variant. BM=BN=128, BK=32, 256 thr
// (4 waves, 64x64/wave). 2-slot LDS ring (32 KB) + launch_bounds(256,4)
// -> 4 blocks/CU (rate law: 6.4/8.3/9.9 TB/s @1/2/3 streams; extrapolate
// ~12 @4). m97 drain schedule: {STAGE(t+1); ds_read(t); MFMA; vmcnt(0);
// one s_barrier}. Zero-conflict chunk swizzle. setprio on MFMA cluster.
// MODE 0: bf16 out. MODE 1: f32 out = res + v. MODE 2: bf16 swish(v).
// MODE 3: bf16 out written to VT layout [B*H][DK][S] (fused v-transpose).
template <int MODE>
__global__ __launch_bounds__(256, 4) void gemm_bt(
    const bf16* __restrict__ A, const bf16* __restrict__ WT,
    const float* __restrict__ bias, const float* __restrict__ res,
    void* __restrict__ out, int M, int N, int K) {
  __shared__ bf16 SA[2][128 * 32];  // 16 KiB
  __shared__ bf16 SB[2][128 * 32];  // 16 KiB
  const int t = threadIdx.x;
  const int w = t >> 6, l = t & 63;
  const int wr = w >> 1, wc = w & 1;
  const int c = l & 15, g = l >> 4;
  const long row0 = (long)blockIdx.x * 128;
  const long col0 = (long)blockIdx.y * 128;
  const int NT = K >> 5;

  f32x4 acc[4][4];
#pragma unroll
  for (int m = 0; m < 4; ++m)
#pragma unroll
    for (int n = 0; n < 4; ++n) acc[m][n] = (f32x4){0.f, 0.f, 0.f, 0.f};

  // staging: lane -> row l>>2, dest slot l&3, src slot (l&3)^((row>>1)&3)
  const int srow = l >> 2;
  const int sslot = 8 * ((l & 3) ^ ((l >> 3) & 3));
  const bf16* Ag0 = A + (row0 + w * 16 + srow) * (long)K + sslot;
  const bf16* Ag1 = Ag0 + 64 * (long)K;
  const bf16* Bg0 = WT + (col0 + w * 16 + srow) * (long)K + sslot;
  const bf16* Bg1 = Bg0 + 64 * (long)K;
  bf16* const SAf = &SA[0][0];
  bf16* const SBf = &SB[0][0];

#define STAGE(SL, KK)                                            \
  do {                                                           \
    gload16(Ag0 + (KK), SAf + (SL) * 4096 + (w * 16) * 32);      \
    gload16(Ag1 + (KK), SAf + (SL) * 4096 + (64 + w * 16) * 32); \
    gload16(Bg0 + (KK), SBf + (SL) * 4096 + (w * 16) * 32);      \
    gload16(Bg1 + (KK), SBf + (SL) * 4096 + (64 + w * 16) * 32); \
  } while (0)

  // read offsets (element units), loop-invariant
  const int rsw = (g ^ ((c >> 1) & 3)) * 8;
  int aoff[4], boff[4];
#pragma unroll
  for (int m = 0; m < 4; ++m) aoff[m] = (wr * 64 + m * 16 + c) * 32 + rsw;
#pragma unroll
  for (int n = 0; n < 4; ++n) boff[n] = (wc * 64 + n * 16 + c) * 32 + rsw;

  // prologue: tile 0
  STAGE(0, 0);
  asm volatile("s_waitcnt vmcnt(0)" ::: "memory");
  __builtin_amdgcn_s_barrier();

  for (int tt = 0; tt < NT; ++tt) {
    if (tt + 1 < NT) STAGE((tt + 1) & 1, (tt + 1) << 5);

    const int ca = (tt & 1) * 4096;
    bf16x8 af[4], bfr[4];
#pragma unroll
    for (int m = 0; m < 4; ++m) af[m] = *(const bf16x8*)(SAf + ca + aoff[m]);
#pragma unroll
    for (int n = 0; n < 4; ++n) bfr[n] = *(const bf16x8*)(SBf + ca + boff[n]);

    __builtin_amdgcn_s_setprio(1);
#pragma unroll
    for (int m = 0; m < 4; ++m)
#pragma unroll
      for (int n = 0; n < 4; ++n)
        acc[m][n] = __builtin_amdgcn_mfma_f32_16x16x32_bf16(af[m], bfr[n], acc[m][n], 0, 0, 0);
    __builtin_amdgcn_s_setprio(0);

    if (tt + 1 < NT) {
      asm volatile("s_waitcnt vmcnt(0)" ::: "memory");  // tile t+1 landed
    }
    __builtin_amdgcn_s_barrier();  // publish; also orders slot reuse
  }
#undef STAGE

  if (MODE == 3) {
    bf16* VT = (bf16*)out;
#pragma unroll
    for (int n = 0; n < 4; ++n) {
      const long col = col0 + wc * 64 + n * 16 + c;
      const float bv = bias[col];
      const long h = col >> 6, dk = col & 63;
#pragma unroll
      for (int m = 0; m < 4; ++m) {
        const long rowb = row0 + wr * 64 + m * 16 + g * 4;
        const long b = rowb >> 10, s = rowb & 1023;
        bf16x4 ov;
#pragma unroll
        for (int r = 0; r < 4; ++r) ov[r] = (bf16)(acc[m][n][r] + bv);
        *(bf16x4*)(VT + (((b * NH + h) * NDK + dk) << 10) + s) = ov;
      }
    }
    return;
  }

#pragma unroll
  for (int n = 0; n < 4; ++n) {
    const long col = col0 + wc * 64 + n * 16 + c;
    const float bv = bias[col];
#pragma unroll
    for (int m = 0; m < 4; ++m) {
      const long rowb = row0 + wr * 64 + m * 16 + g * 4;
#pragma unroll
      for (int r = 0; r < 4; ++r) {
        float v = acc[m][n][r] + bv;
        const long idx = (rowb + r) * N + col;
        if (MODE == 0) {
          ((bf16*)out)[idx] = (bf16)v;
        } else if (MODE == 1) {
          ((float*)out)[idx] = res[idx] + v;
        } else {
          float sw = v / (1.f + __expf(-v));
          ((bf16*)out)[idx] = (bf16)sw;
        }
      }
    }
  }
}

// ---- GEMM v6-w8 (unchanged, FFN1): BM=256, BN=128, BK=32, 512 thr.
// 3-slot ring (72 KB -> 2 blocks/CU); counted vmcnt(3). Measured 95us FFN1.
template <int MODE>
__global__ __launch_bounds__(512) void gemm_bt8(
    const bf16* __restrict__ A, const bf16* __restrict__ WT,
    const float* __restrict__ bias, const float* __restrict__ res,
    void* __restrict__ out, int M, int N, int K) {
  __shared__ bf16 SA[3][256 * 32];  // 48 KiB
  __shared__ bf16 SB[3][128 * 32];  // 24 KiB
  const int t = threadIdx.x;
  const int w = t >> 6, l = t & 63;
  const int wr = w >> 1, wc = w & 1;
  const int c = l & 15, g = l >> 4;
  const long row0 = (long)blockIdx.x * 256;
  const long col0 = (long)blockIdx.y * 128;
  const int NT = K >> 5;

  f32x4 acc[4][4];
#pragma unroll
  for (int m = 0; m < 4; ++m)
#pragma unroll
    for (int n = 0; n < 4; ++n) acc[m][n] = (f32x4){0.f, 0.f, 0.f, 0.f};

  const int srow = l >> 2;
  const int sslot = 8 * ((l & 3) ^ ((l >> 3) & 3));
  const bf16* Ag0 = A + (row0 + w * 16 + srow) * (long)K + sslot;
  const bf16* Ag1 = Ag0 + 128 * (long)K;
  const bf16* Bg0 = WT + (col0 + w * 16 + srow) * (long)K + sslot;
  bf16* const SAf = &SA[0][0];
  bf16* const SBf = &SB[0][0];

#define STAGE8(SL, KK)                                            \
  do {                                                            \
    gload16(Ag0 + (KK), SAf + (SL) * 8192 + (w * 16) * 32);       \
    gload16(Ag1 + (KK), SAf + (SL) * 8192 + (128 + w * 16) * 32); \
    gload16(Bg0 + (KK), SBf + (SL) * 4096 + (w * 16) * 32);       \
  } while (0)

  STAGE8(0, 0);
  STAGE8(1, 32);

  const int rsw = (g ^ ((c >> 1) & 3)) * 8;
  int aoff[4], boff[4];
#pragma unroll
  for (int m = 0; m < 4; ++m) aoff[m] = (wr * 64 + m * 16 + c) * 32 + rsw;
#pragma unroll
  for (int n = 0; n < 4; ++n) boff[n] = (wc * 64 + n * 16 + c) * 32 + rsw;

  asm volatile("s_waitcnt vmcnt(3)" ::: "memory");
  __builtin_amdgcn_s_barrier();

  int cb = 0, sb = 2, kst = 64;
  for (int tt = 0; tt < NT; ++tt) {
    bf16x8 af[4], bfr[4];
#pragma unroll
    for (int m = 0; m < 4; ++m) af[m] = *(const bf16x8*)(SAf + cb * 8192 + aoff[m]);
#pragma unroll
    for (int n = 0; n < 4; ++n) bfr[n] = *(const bf16x8*)(SBf + cb * 4096 + boff[n]);

    if (tt + 2 < NT) STAGE8(sb, kst);

    __builtin_amdgcn_s_barrier();
    asm volatile("s_waitcnt lgkmcnt(0)" ::: "memory");
    __builtin_amdgcn_sched_barrier(0);
    __builtin_amdgcn_s_setprio(1);
#pragma unroll
    for (int m = 0; m < 4; ++m)
#pragma unroll
      for (int n = 0; n < 4; ++n)
        acc[m][n] = __builtin_amdgcn_mfma_f32_16x16x32_bf16(af[m], bfr[n], acc[m][n], 0, 0, 0);
    __builtin_amdgcn_s_setprio(0);

    if (tt + 2 < NT) {
      asm volatile("s_waitcnt vmcnt(3)" ::: "memory");
    } else {
      asm volatile("s_waitcnt vmcnt(0)" ::: "memory");
    }
    __builtin_amdgcn_s_barrier();

    cb = (cb == 2) ? 0 : cb + 1;
    sb = (sb == 2) ? 0 : sb + 1;
    kst += 32;
  }
#undef STAGE8

#pragma unroll
  for (int n = 0; n < 4; ++n) {
    const long col = col0 + wc * 64 + n * 16 + c;
    const float bv = bias[col];
#pragma unroll
    for (int m = 0; m < 4; ++m) {
      const long rowb = row0 + wr * 64 + m * 16 + g * 4;
#pragma unroll
      for (int r = 0; r < 4; ++r) {
        float v = acc[m][n][r] + bv;
        const long idx = (rowb + r) * N + col;
        if (MODE == 0) {
          ((bf16*)out)[idx] = (bf16)v;
        } else if (MODE == 1) {
          ((float*)out)[idx] = res[idx] + v;
        } else {
          float sw = v / (1.f + __expf(-v));
          ((bf16*)out)[idx] = (bf16)sw;
        }
      }
    }
  }
}

// ---- flash attention v4 (unchanged): counted-vmcnt prefetch pipeline ----
__global__ __launch_bounds__(256) void attn_fwd(
    const bf16* __restrict__ Q, const bf16* __restrict__ Kt,
    const bf16* __restrict__ VT, bf16* __restrict__ O) {
  __shared__ bf16 Ks[2][64 * 64];
  __shared__ bf16 Vs[2][64 * 64];
  __shared__ bf16 Pl[4][2][16 * 68];
  int t = threadIdx.x;
  int w = t >> 6, l = t & 63;
  int c = l & 15, g = l >> 4;
  int bid = blockIdx.x;
  int qt = bid >> 7, bh = bid & 127;
  int b = bh >> 4, h = bh & 15;
  int q0 = qt * 128 + w * 32;
  int swz = (c & 7) << 4;

  bf16x8 qf[2][2];
  const bf16* Qbase = Q + (long)(b * NS) * ND + h * NDK;
#pragma unroll
  for (int sj = 0; sj < 2; ++sj) {
    const bf16* qr = Qbase + (long)(q0 + sj * 16 + c) * ND + g * 8;
    qf[sj][0] = *(const bf16x8*)qr;
    qf[sj][1] = *(const bf16x8*)(qr + 32);
  }

  const bf16* Kg = Kt + (long)(b * NS) * ND + h * NDK;
  const bf16* Vg = VT + (long)(b * NH + h) * NDK * NS;

  int sr = l >> 3;
  int sc8 = 8 * ((l & 7) ^ sr);

  f32x4 o[2][4];
#pragma unroll
  for (int sj = 0; sj < 2; ++sj)
#pragma unroll
    for (int ds = 0; ds < 4; ++ds) o[sj][ds] = (f32x4){0.f, 0.f, 0.f, 0.f};
  float mx[2] = {-1e30f, -1e30f};
  float lsum[2] = {0.f, 0.f};

#define STAGE(BUF, KV)                                                        \
  {                                                                           \
    _Pragma("unroll") for (int j = 0; j < 2; ++j) {                           \
      int row = w * 16 + j * 8 + sr;                                          \
      gload16(Kg + (long)((KV) + row) * ND + sc8,                             \
              &Ks[BUF][(w * 16 + j * 8) * 64]);                               \
      gload16(Vg + (long)row * NS + (KV) + sc8,                               \
              &Vs[BUF][(w * 16 + j * 8) * 64]);                               \
    }                                                                         \
  }

  STAGE(0, 0);

  int buf = 0;
  for (int it = 0; it < NS / 64; ++it) {
    if (it + 1 < NS / 64) {
      STAGE(buf ^ 1, (it + 1) * 64);
      asm volatile("s_waitcnt vmcnt(4)" ::: "memory");
    } else {
      asm volatile("s_waitcnt vmcnt(0)" ::: "memory");
    }
    __builtin_amdgcn_s_barrier();

    f32x4 sv[2][4];
#pragma unroll
    for (int sj = 0; sj < 2; ++sj)
#pragma unroll
      for (int kt = 0; kt < 4; ++kt) sv[sj][kt] = (f32x4){0.f, 0.f, 0.f, 0.f};
    __builtin_amdgcn_s_setprio(1);
#pragma unroll
    for (int kt = 0; kt < 4; ++kt) {
      const char* kr = (const char*)&Ks[buf][(kt * 16 + c) * 64];
      bf16x8 ka0 = *(const bf16x8*)(kr + ((g * 16) ^ swz));
      bf16x8 ka1 = *(const bf16x8*)(kr + ((64 + g * 16) ^ swz));
#pragma unroll
      for (int sj = 0; sj < 2; ++sj) {
        sv[sj][kt] = __builtin_amdgcn_mfma_f32_16x16x32_bf16(ka0, qf[sj][0], sv[sj][kt], 0, 0, 0);
        sv[sj][kt] = __builtin_amdgcn_mfma_f32_16x16x32_bf16(ka1, qf[sj][1], sv[sj][kt], 0, 0, 0);
      }
    }
    __builtin_amdgcn_s_setprio(0);

    float pm[2];
#pragma unroll
    for (int sj = 0; sj < 2; ++sj) {
      float m = -1e30f;
#pragma unroll
      for (int kt = 0; kt < 4; ++kt)
#pragma unroll
        for (int r = 0; r < 4; ++r) {
          sv[sj][kt][r] *= 0.125f;
          m = fmaxf(m, sv[sj][kt][r]);
        }
      m = fmaxf(m, __shfl_xor(m, 16));
      m = fmaxf(m, __shfl_xor(m, 32));
      pm[sj] = m;
    }
    int cond = (pm[0] <= mx[0] + 8.f) && (pm[1] <= mx[1] + 8.f);
    if (!__all(cond)) {
#pragma unroll
      for (int sj = 0; sj < 2; ++sj) {
        float mn = fmaxf(mx[sj], pm[sj]);
        float sc = __expf(mx[sj] - mn);
        mx[sj] = mn;
        lsum[sj] *= sc;
#pragma unroll
        for (int ds = 0; ds < 4; ++ds)
#pragma unroll
          for (int r = 0; r < 4; ++r) o[sj][ds][r] *= sc;
      }
    }
#pragma unroll
    for (int sj = 0; sj < 2; ++sj) {
      float rs = 0.f;
#pragma unroll
      for (int kt = 0; kt < 4; ++kt) {
        bf16x4 pw;
#pragma unroll
        for (int r = 0; r < 4; ++r) {
          float e = __expf(sv[sj][kt][r] - mx[sj]);
          rs += e;
          pw[r] = (bf16)e;
        }
        *(bf16x4*)&Pl[w][sj][c * 68 + kt * 16 + 4 * g] = pw;
      }
      rs += __shfl_xor(rs, 16);
      rs += __shfl_xor(rs, 32);
      lsum[sj] += rs;
    }
    asm volatile("s_waitcnt lgkmcnt(0)" ::: "memory");
    __builtin_amdgcn_sched_barrier(0);

    __builtin_amdgcn_s_setprio(1);
#pragma unroll
    for (int ks = 0; ks < 2; ++ks) {
      bf16x8 pb0 = *(const bf16x8*)&Pl[w][0][c * 68 + ks * 32 + g * 8];
      bf16x8 pb1 = *(const bf16x8*)&Pl[w][1][c * 68 + ks * 32 + g * 8];
#pragma unroll
      for (int ds = 0; ds < 4; ++ds) {
        const char* vr = (const char*)&Vs[buf][(ds * 16 + c) * 64];
        bf16x8 va = *(const bf16x8*)(vr + ((ks * 64 + g * 16) ^ swz));
        o[0][ds] = __builtin_amdgcn_mfma_f32_16x16x32_bf16(va, pb0, o[0][ds], 0, 0, 0);
        o[1][ds] = __builtin_amdgcn_mfma_f32_16x16x32_bf16(va, pb1, o[1][ds], 0, 0, 0);
      }
    }
    __builtin_amdgcn_s_setprio(0);
    __builtin_amdgcn_s_barrier();
    buf ^= 1;
  }

#pragma unroll
  for (int sj = 0; sj < 2; ++sj) {
    float inv = 1.f / lsum[sj];
    bf16* Orow = O + (long)(b * NS + q0 + sj * 16 + c) * ND + h * NDK;
#pragma unroll
    for (int ds = 0; ds < 4; ++ds) {
      bf16x4 ov;
#pragma unroll
      for (int r = 0; r < 4; ++r) ov[r] = (bf16)(o[sj][ds][r] * inv);
      *(bf16x4*)(Orow + ds * 16 + 4 * g) = ov;
    }
  }
#undef STAGE
}

extern "C" void kernel_launch(void* const* d_in, const int* in_sizes, int n_in,
                              void* d_out, int out_size, void* d_ws, size_t ws_size,
                              hipStream_t stream) {
  (void)in_sizes; (void)n_in; (void)out_size; (void)ws_size;
  const float* x = (const float*)d_in[0];
  const float* y = (const float*)d_in[1];
  const float* x_pos = (const float*)d_in[2];
  const float* y_pos = (const float*)d_in[3];

  char* ws = (char*)d_ws;
  const size_t MB = 1ull << 20;
  bf16* Wt[8];
  for (int i = 0; i < 8; ++i) Wt[i] = (bf16*)(ws + (size_t)i * 2 * MB);
  bf16* W1T = (bf16*)(ws + 16 * MB);
  bf16* W2T = (bf16*)(ws + 24 * MB);
  float* xres = (float*)(ws + 32 * MB);
  bf16* x2 = (bf16*)(ws + 64 * MB);
  bf16* qk = (bf16*)(ws + 80 * MB);
  bf16* y2 = (bf16*)(ws + 96 * MB);
  bf16* yk = (bf16*)(ws + 112 * MB);
  bf16* Qb = (bf16*)(ws + 128 * MB);
  bf16* Kb = (bf16*)(ws + 144 * MB);
  bf16* VTb = (bf16*)(ws + 176 * MB);
  bf16* Ob = (bf16*)(ws + 192 * MB);
  bf16* hb = (bf16*)(ws + 128 * MB);  // aliases Qb..VTb (free during FFN)

  dim3 tb(32, 8);
  WPtrs wp;
  for (int i = 0; i < 8; ++i) wp.w[i] = (const float*)d_in[4 + 2 * i];
  wconv8<<<dim3(32, 32, 8), tb, 0, stream>>>(wp, (bf16*)ws);
  wconv_t<<<dim3(128, 32), tb, 0, stream>>>((const float*)d_in[20], W1T, 1024, 4096);
  wconv_t<<<dim3(32, 128), tb, 0, stream>>>((const float*)d_in[22], W2T, 4096, 1024);

  const float* ln1g = (const float*)d_in[24]; const float* ln1b = (const float*)d_in[25];
  const float* ln2g = (const float*)d_in[26]; const float* ln2b = (const float*)d_in[27];
  const float* ln3g = (const float*)d_in[28]; const float* ln3b = (const float*)d_in[29];
  const float* ln4g = (const float*)d_in[30]; const float* ln4b = (const float*)d_in[31];

  dim3 gD(64, 8);      // 128^2 tiles
  dim3 gF1(32, 32);    // 256x128 tiles for FFN1

  // ---- self-attention ----
  ln_fused<<<8192, 256, 0, stream>>>(x, ln1g, ln1b, x_pos, x2, qk);
  gemm_bt<0><<<gD, 256, 0, stream>>>(qk, Wt[0], (const float*)d_in[5], nullptr, Qb, 8192, 1024, 1024);
  gemm_bt<0><<<gD, 256, 0, stream>>>(qk, Wt[1], (const float*)d_in[7], nullptr, Kb, 8192, 1024, 1024);
  gemm_bt<3><<<gD, 256, 0, stream>>>(x2, Wt[2], (const float*)d_in[9], nullptr, VTb, 8192, 1024, 1024);
  attn_fwd<<<1024, 256, 0, stream>>>(Qb, Kb, VTb, Ob);
  gemm_bt<1><<<gD, 256, 0, stream>>>(Ob, Wt[3], (const float*)d_in[11], x, xres, 8192, 1024, 1024);

  // ---- cross-attention ----
  ln_fused<<<8192, 256, 0, stream>>>(xres, ln2g, ln2b, x_pos, nullptr, qk);
  ln_fused<<<8192, 256, 0, stream>>>(y, ln3g, ln3b, y_pos, y2, yk);
  gemm_bt<0><<<gD, 256, 0, stream>>>(qk, Wt[4], (const float*)d_in[13], nullptr, Qb, 8192, 1024, 1024);
  gemm_bt<0><<<gD, 256, 0, stream>>>(yk, Wt[5], (const float*)d_in[15], nullptr, Kb, 8192, 1024, 1024);
  gemm_bt<3><<<gD, 256, 0, stream>>>(y2, Wt[6], (const float*)d_in[17], nullptr, VTb, 8192, 1024, 1024);
  attn_fwd<<<1024, 256, 0, stream>>>(Qb, Kb, VTb, Ob);
  gemm_bt<1><<<gD, 256, 0, stream>>>(Ob, Wt[7], (const float*)d_in[19], xres, xres, 8192, 1024, 1024);

  // ---- FFN ----
  ln_fused<<<8192, 256, 0, stream>>>(xres, ln4g, ln4b, nullptr, x2, nullptr);
  gemm_bt8<2><<<gF1, 512, 0, stream>>>(x2, W1T, (const float*)d_in[21], nullptr, hb, 8192, 4096, 1024);
  gemm_bt<1><<<gD, 256, 0, stream>>>(hb, W2T, (const float*)d_in[23], xres, (float*)d_out, 8192, 1024, 4096);
}

// Round 14
// 614.021 us; speedup vs baseline: 1.1633x; 1.1633x over previous
//
#include <hip/hip_runtime.h>
#include <hip/hip_bf16.h>

#define NB 8
#define NS 1024
#define ND 1024
#define NH 16
#define NDK 64
#define NDFF 4096

typedef __bf16 bf16;
typedef __attribute__((ext_vector_type(8))) __bf16 bf16x8;
typedef __attribute__((ext_vector_type(4))) __bf16 bf16x4;
typedef __attribute__((ext_vector_type(4))) float f32x4;

__device__ __forceinline__ void gload16(const bf16* g, bf16* l) {
  __builtin_amdgcn_global_load_lds(
      (const __attribute__((address_space(1))) void*)g,
      (__attribute__((address_space(3))) void*)l, 16, 0, 0);
}

// ---- weight convert + transpose: W f32 [K][N] -> WT bf16 [N][K] ----
__global__ void wconv_t(const float* __restrict__ W, bf16* __restrict__ WT,
                        int K, int N) {
  __shared__ float tile[32][33];
  int n0 = blockIdx.x * 32, k0 = blockIdx.y * 32;
  int tx = threadIdx.x, ty = threadIdx.y;
#pragma unroll
  for (int i2 = 0; i2 < 4; ++i2) {
    int i = ty + i2 * 8;
    tile[i][tx] = W[(long)(k0 + i) * N + n0 + tx];
  }
  __syncthreads();
#pragma unroll
  for (int i2 = 0; i2 < 4; ++i2) {
    int i = ty + i2 * 8;
    WT[(long)(n0 + i) * K + k0 + tx] = (bf16)tile[tx][i];
  }
}

// ---- fused 8x square (1024x1024) weight convert in one launch ----
struct WPtrs { const float* w[8]; };
__global__ void wconv8(WPtrs wp, bf16* __restrict__ dst) {
  __shared__ float tile[32][33];
  int n0 = blockIdx.x * 32, k0 = blockIdx.y * 32;
  const float* W = wp.w[blockIdx.z];
  bf16* WT = dst + (size_t)blockIdx.z * (1024 * 1024);
  int tx = threadIdx.x, ty = threadIdx.y;
#pragma unroll
  for (int i2 = 0; i2 < 4; ++i2) {
    int i = ty + i2 * 8;
    tile[i][tx] = W[(long)(k0 + i) * 1024 + n0 + tx];
  }
  __syncthreads();
#pragma unroll
  for (int i2 = 0; i2 < 4; ++i2) {
    int i = ty + i2 * 8;
    WT[(long)(n0 + i) * 1024 + k0 + tx] = (bf16)tile[tx][i];
  }
}

// ---- fused layernorm: out_ln = bf16(LN(x)), out_lnpos = bf16(LN(x)+pos) ----
__global__ void ln_fused(const float* __restrict__ in, const float* __restrict__ gam,
                         const float* __restrict__ bet, const float* __restrict__ pos,
                         bf16* __restrict__ out_ln, bf16* __restrict__ out_lnpos) {
  long row = blockIdx.x;
  int t = threadIdx.x;  // 256
  float4 v = ((const float4*)(in + row * ND))[t];
  float s = v.x + v.y + v.z + v.w;
  float s2 = v.x * v.x + v.y * v.y + v.z * v.z + v.w * v.w;
#pragma unroll
  for (int m = 32; m >= 1; m >>= 1) {
    s += __shfl_xor(s, m);
    s2 += __shfl_xor(s2, m);
  }
  __shared__ float red[8];
  if ((t & 63) == 0) {
    red[t >> 6] = s;
    red[4 + (t >> 6)] = s2;
  }
  __syncthreads();
  float ts = red[0] + red[1] + red[2] + red[3];
  float ts2 = red[4] + red[5] + red[6] + red[7];
  float mu = ts * (1.0f / ND);
  float var = ts2 * (1.0f / ND) - mu * mu;
  float rstd = rsqrtf(var + 1e-5f);
  float4 g4 = ((const float4*)gam)[t];
  float4 b4 = ((const float4*)bet)[t];
  float o0 = (v.x - mu) * rstd * g4.x + b4.x;
  float o1 = (v.y - mu) * rstd * g4.y + b4.y;
  float o2 = (v.z - mu) * rstd * g4.z + b4.z;
  float o3 = (v.w - mu) * rstd * g4.w + b4.w;
  if (out_ln) {
    bf16x4 q;
    q[0] = (bf16)o0; q[1] = (bf16)o1; q[2] = (bf16)o2; q[3] = (bf16)o3;
    *(bf16x4*)(out_ln + row * ND + t * 4) = q;
  }
  if (out_lnpos) {
    float4 p4 = ((const float4*)(pos + row * ND))[t];
    bf16x4 q;
    q[0] = (bf16)(o0 + p4.x); q[1] = (bf16)(o1 + p4.y);
    q[2] = (bf16)(o2 + p4.z); q[3] = (bf16)(o3 + p4.w);
    *(bf16x4*)(out_lnpos + row * ND + t * 4) = q;
  }
}

// ---- GEMM v6 (round-12 proven best): BM=BN=128, BK=32, 256 thr (4 waves,
// 64x64/wave). 3-slot LDS ring (48 KB -> 3 blocks/CU). Stage tile t+2
// during t; counted vmcnt(4). Zero-conflict chunk swizzle.
// MODE 0: bf16 out. MODE 1: f32 out = res + v. MODE 2: bf16 swish(v).
// MODE 3: bf16 out written to VT layout [B*H][DK][S] (fused v-transpose).
template <int MODE>
__global__ __launch_bounds__(256) void gemm_bt(
    const bf16* __restrict__ A, const bf16* __restrict__ WT,
    const float* __restrict__ bias, const float* __restrict__ res,
    void* __restrict__ out, int M, int N, int K) {
  __shared__ bf16 SA[3][128 * 32];  // 24 KiB
  __shared__ bf16 SB[3][128 * 32];  // 24 KiB
  const int t = threadIdx.x;
  const int w = t >> 6, l = t & 63;
  const int wr = w >> 1, wc = w & 1;
  const int c = l & 15, g = l >> 4;
  const long row0 = (long)blockIdx.x * 128;
  const long col0 = (long)blockIdx.y * 128;
  const int NT = K >> 5;

  f32x4 acc[4][4];
#pragma unroll
  for (int m = 0; m < 4; ++m)
#pragma unroll
    for (int n = 0; n < 4; ++n) acc[m][n] = (f32x4){0.f, 0.f, 0.f, 0.f};

  const int srow = l >> 2;
  const int sslot = 8 * ((l & 3) ^ ((l >> 3) & 3));
  const bf16* Ag0 = A + (row0 + w * 16 + srow) * (long)K + sslot;
  const bf16* Ag1 = Ag0 + 64 * (long)K;
  const bf16* Bg0 = WT + (col0 + w * 16 + srow) * (long)K + sslot;
  const bf16* Bg1 = Bg0 + 64 * (long)K;
  bf16* const SAf = &SA[0][0];
  bf16* const SBf = &SB[0][0];

#define STAGE(SL, KK)                                            \
  do {                                                           \
    gload16(Ag0 + (KK), SAf + (SL) * 4096 + (w * 16) * 32);      \
    gload16(Ag1 + (KK), SAf + (SL) * 4096 + (64 + w * 16) * 32); \
    gload16(Bg0 + (KK), SBf + (SL) * 4096 + (w * 16) * 32);      \
    gload16(Bg1 + (KK), SBf + (SL) * 4096 + (64 + w * 16) * 32); \
  } while (0)

  STAGE(0, 0);
  STAGE(1, 32);

  const int rsw = (g ^ ((c >> 1) & 3)) * 8;
  int aoff[4], boff[4];
#pragma unroll
  for (int m = 0; m < 4; ++m) aoff[m] = (wr * 64 + m * 16 + c) * 32 + rsw;
#pragma unroll
  for (int n = 0; n < 4; ++n) boff[n] = (wc * 64 + n * 16 + c) * 32 + rsw;

  asm volatile("s_waitcnt vmcnt(4)" ::: "memory");
  __builtin_amdgcn_s_barrier();

  int cb = 0, sb = 2, kst = 64;
  for (int tt = 0; tt < NT; ++tt) {
    const int ca = cb * 4096;
    bf16x8 af[4], bfr[4];
#pragma unroll
    for (int m = 0; m < 4; ++m) af[m] = *(const bf16x8*)(SAf + ca + aoff[m]);
#pragma unroll
    for (int n = 0; n < 4; ++n) bfr[n] = *(const bf16x8*)(SBf + ca + boff[n]);

    if (tt + 2 < NT) STAGE(sb, kst);

    __builtin_amdgcn_s_barrier();
    asm volatile("s_waitcnt lgkmcnt(0)" ::: "memory");
    __builtin_amdgcn_sched_barrier(0);
    __builtin_amdgcn_s_setprio(1);
#pragma unroll
    for (int m = 0; m < 4; ++m)
#pragma unroll
      for (int n = 0; n < 4; ++n)
        acc[m][n] = __builtin_amdgcn_mfma_f32_16x16x32_bf16(af[m], bfr[n], acc[m][n], 0, 0, 0);
    __builtin_amdgcn_s_setprio(0);

    if (tt + 2 < NT) {
      asm volatile("s_waitcnt vmcnt(4)" ::: "memory");
    } else {
      asm volatile("s_waitcnt vmcnt(0)" ::: "memory");
    }
    __builtin_amdgcn_s_barrier();

    cb = (cb == 2) ? 0 : cb + 1;
    sb = (sb == 2) ? 0 : sb + 1;
    kst += 32;
  }
#undef STAGE

  if (MODE == 3) {
    bf16* VT = (bf16*)out;
#pragma unroll
    for (int n = 0; n < 4; ++n) {
      const long col = col0 + wc * 64 + n * 16 + c;
      const float bv = bias[col];
      const long h = col >> 6, dk = col & 63;
#pragma unroll
      for (int m = 0; m < 4; ++m) {
        const long rowb = row0 + wr * 64 + m * 16 + g * 4;
        const long b = rowb >> 10, s = rowb & 1023;
        bf16x4 ov;
#pragma unroll
        for (int r = 0; r < 4; ++r) ov[r] = (bf16)(acc[m][n][r] + bv);
        *(bf16x4*)(VT + (((b * NH + h) * NDK + dk) << 10) + s) = ov;
      }
    }
    return;
  }

#pragma unroll
  for (int n = 0; n < 4; ++n) {
    const long col = col0 + wc * 64 + n * 16 + c;
    const float bv = bias[col];
#pragma unroll
    for (int m = 0; m < 4; ++m) {
      const long rowb = row0 + wr * 64 + m * 16 + g * 4;
#pragma unroll
      for (int r = 0; r < 4; ++r) {
        float v = acc[m][n][r] + bv;
        const long idx = (rowb + r) * N + col;
        if (MODE == 0) {
          ((bf16*)out)[idx] = (bf16)v;
        } else if (MODE == 1) {
          ((float*)out)[idx] = res[idx] + v;
        } else {
          float sw = v / (1.f + __expf(-v));
          ((bf16*)out)[idx] = (bf16)sw;
        }
      }
    }
  }
}

// ---- GEMM v6-w8 (unchanged, FFN1): BM=256, BN=128, BK=32, 512 thr.
// 3-slot ring (72 KB -> 2 blocks/CU); counted vmcnt(3). Measured 95us FFN1.
template <int MODE>
__global__ __launch_bounds__(512) void gemm_bt8(
    const bf16* __restrict__ A, const bf16* __restrict__ WT,
    const float* __restrict__ bias, const float* __restrict__ res,
    void* __restrict__ out, int M, int N, int K) {
  __shared__ bf16 SA[3][256 * 32];  // 48 KiB
  __shared__ bf16 SB[3][128 * 32];  // 24 KiB
  const int t = threadIdx.x;
  const int w = t >> 6, l = t & 63;
  const int wr = w >> 1, wc = w & 1;
  const int c = l & 15, g = l >> 4;
  const long row0 = (long)blockIdx.x * 256;
  const long col0 = (long)blockIdx.y * 128;
  const int NT = K >> 5;

  f32x4 acc[4][4];
#pragma unroll
  for (int m = 0; m < 4; ++m)
#pragma unroll
    for (int n = 0; n < 4; ++n) acc[m][n] = (f32x4){0.f, 0.f, 0.f, 0.f};

  const int srow = l >> 2;
  const int sslot = 8 * ((l & 3) ^ ((l >> 3) & 3));
  const bf16* Ag0 = A + (row0 + w * 16 + srow) * (long)K + sslot;
  const bf16* Ag1 = Ag0 + 128 * (long)K;
  const bf16* Bg0 = WT + (col0 + w * 16 + srow) * (long)K + sslot;
  bf16* const SAf = &SA[0][0];
  bf16* const SBf = &SB[0][0];

#define STAGE8(SL, KK)                                            \
  do {                                                            \
    gload16(Ag0 + (KK), SAf + (SL) * 8192 + (w * 16) * 32);       \
    gload16(Ag1 + (KK), SAf + (SL) * 8192 + (128 + w * 16) * 32); \
    gload16(Bg0 + (KK), SBf + (SL) * 4096 + (w * 16) * 32);       \
  } while (0)

  STAGE8(0, 0);
  STAGE8(1, 32);

  const int rsw = (g ^ ((c >> 1) & 3)) * 8;
  int aoff[4], boff[4];
#pragma unroll
  for (int m = 0; m < 4; ++m) aoff[m] = (wr * 64 + m * 16 + c) * 32 + rsw;
#pragma unroll
  for (int n = 0; n < 4; ++n) boff[n] = (wc * 64 + n * 16 + c) * 32 + rsw;

  asm volatile("s_waitcnt vmcnt(3)" ::: "memory");
  __builtin_amdgcn_s_barrier();

  int cb = 0, sb = 2, kst = 64;
  for (int tt = 0; tt < NT; ++tt) {
    bf16x8 af[4], bfr[4];
#pragma unroll
    for (int m = 0; m < 4; ++m) af[m] = *(const bf16x8*)(SAf + cb * 8192 + aoff[m]);
#pragma unroll
    for (int n = 0; n < 4; ++n) bfr[n] = *(const bf16x8*)(SBf + cb * 4096 + boff[n]);

    if (tt + 2 < NT) STAGE8(sb, kst);

    __builtin_amdgcn_s_barrier();
    asm volatile("s_waitcnt lgkmcnt(0)" ::: "memory");
    __builtin_amdgcn_sched_barrier(0);
    __builtin_amdgcn_s_setprio(1);
#pragma unroll
    for (int m = 0; m < 4; ++m)
#pragma unroll
      for (int n = 0; n < 4; ++n)
        acc[m][n] = __builtin_amdgcn_mfma_f32_16x16x32_bf16(af[m], bfr[n], acc[m][n], 0, 0, 0);
    __builtin_amdgcn_s_setprio(0);

    if (tt + 2 < NT) {
      asm volatile("s_waitcnt vmcnt(3)" ::: "memory");
    } else {
      asm volatile("s_waitcnt vmcnt(0)" ::: "memory");
    }
    __builtin_amdgcn_s_barrier();

    cb = (cb == 2) ? 0 : cb + 1;
    sb = (sb == 2) ? 0 : sb + 1;
    kst += 32;
  }
#undef STAGE8

#pragma unroll
  for (int n = 0; n < 4; ++n) {
    const long col = col0 + wc * 64 + n * 16 + c;
    const float bv = bias[col];
#pragma unroll
    for (int m = 0; m < 4; ++m) {
      const long rowb = row0 + wr * 64 + m * 16 + g * 4;
#pragma unroll
      for (int r = 0; r < 4; ++r) {
        float v = acc[m][n][r] + bv;
        const long idx = (rowb + r) * N + col;
        if (MODE == 0) {
          ((bf16*)out)[idx] = (bf16)v;
        } else if (MODE == 1) {
          ((float*)out)[idx] = res[idx] + v;
        } else {
          float sw = v / (1.f + __expf(-v));
          ((bf16*)out)[idx] = (bf16)sw;
        }
      }
    }
  }
}

// ---- flash attention v5: QBLK=256 via 8 waves/block (halves K/V re-staging).
// 512 thr, grid 512 (= 2 blocks/CU exactly). Per wave: 32 q-rows, same
// swapped-operand in-register softmax as v4. STAGE: each wave loads 8 K-rows
// + 8 V-rows (2 gloads/thread); counted vmcnt(2); raw barriers.
__global__ __launch_bounds__(512) void attn_fwd(
    const bf16* __restrict__ Q, const bf16* __restrict__ Kt,
    const bf16* __restrict__ VT, bf16* __restrict__ O) {
  __shared__ bf16 Ks[2][64 * 64];
  __shared__ bf16 Vs[2][64 * 64];
  __shared__ bf16 Pl[8][2][16 * 68];
  int t = threadIdx.x;
  int w = t >> 6, l = t & 63;
  int c = l & 15, g = l >> 4;
  int bid = blockIdx.x;
  int qt = bid >> 7, bh = bid & 127;
  int b = bh >> 4, h = bh & 15;
  int q0 = qt * 256 + w * 32;
  int swz = (c & 7) << 4;

  bf16x8 qf[2][2];
  const bf16* Qbase = Q + (long)(b * NS) * ND + h * NDK;
#pragma unroll
  for (int sj = 0; sj < 2; ++sj) {
    const bf16* qr = Qbase + (long)(q0 + sj * 16 + c) * ND + g * 8;
    qf[sj][0] = *(const bf16x8*)qr;
    qf[sj][1] = *(const bf16x8*)(qr + 32);
  }

  const bf16* Kg = Kt + (long)(b * NS) * ND + h * NDK;
  const bf16* Vg = VT + (long)(b * NH + h) * NDK * NS;

  int sr = l >> 3;
  int sc8 = 8 * ((l & 7) ^ sr);

  f32x4 o[2][4];
#pragma unroll
  for (int sj = 0; sj < 2; ++sj)
#pragma unroll
    for (int ds = 0; ds < 4; ++ds) o[sj][ds] = (f32x4){0.f, 0.f, 0.f, 0.f};
  float mx[2] = {-1e30f, -1e30f};
  float lsum[2] = {0.f, 0.f};

#define STAGE(BUF, KV)                                                        \
  {                                                                           \
    int row = w * 8 + sr;                                                     \
    gload16(Kg + (long)((KV) + row) * ND + sc8, &Ks[BUF][(w * 8) * 64]);      \
    gload16(Vg + (long)row * NS + (KV) + sc8, &Vs[BUF][(w * 8) * 64]);        \
  }

  STAGE(0, 0);  // 2 loads/thread in flight

  int buf = 0;
  for (int it = 0; it < NS / 64; ++it) {
    if (it + 1 < NS / 64) {
      STAGE(buf ^ 1, (it + 1) * 64);
      asm volatile("s_waitcnt vmcnt(2)" ::: "memory");  // tile it landed
    } else {
      asm volatile("s_waitcnt vmcnt(0)" ::: "memory");
    }
    __builtin_amdgcn_s_barrier();  // publish tile it (raw, keeps prefetch)

    f32x4 sv[2][4];
#pragma unroll
    for (int sj = 0; sj < 2; ++sj)
#pragma unroll
      for (int kt = 0; kt < 4; ++kt) sv[sj][kt] = (f32x4){0.f, 0.f, 0.f, 0.f};
    __builtin_amdgcn_s_setprio(1);
#pragma unroll
    for (int kt = 0; kt < 4; ++kt) {
      const char* kr = (const char*)&Ks[buf][(kt * 16 + c) * 64];
      bf16x8 ka0 = *(const bf16x8*)(kr + ((g * 16) ^ swz));
      bf16x8 ka1 = *(const bf16x8*)(kr + ((64 + g * 16) ^ swz));
#pragma unroll
      for (int sj = 0; sj < 2; ++sj) {
        sv[sj][kt] = __builtin_amdgcn_mfma_f32_16x16x32_bf16(ka0, qf[sj][0], sv[sj][kt], 0, 0, 0);
        sv[sj][kt] = __builtin_amdgcn_mfma_f32_16x16x32_bf16(ka1, qf[sj][1], sv[sj][kt], 0, 0, 0);
      }
    }
    __builtin_amdgcn_s_setprio(0);

    float pm[2];
#pragma unroll
    for (int sj = 0; sj < 2; ++sj) {
      float m = -1e30f;
#pragma unroll
      for (int kt = 0; kt < 4; ++kt)
#pragma unroll
        for (int r = 0; r < 4; ++r) {
          sv[sj][kt][r] *= 0.125f;
          m = fmaxf(m, sv[sj][kt][r]);
        }
      m = fmaxf(m, __shfl_xor(m, 16));
      m = fmaxf(m, __shfl_xor(m, 32));
      pm[sj] = m;
    }
    int cond = (pm[0] <= mx[0] + 8.f) && (pm[1] <= mx[1] + 8.f);
    if (!__all(cond)) {
#pragma unroll
      for (int sj = 0; sj < 2; ++sj) {
        float mn = fmaxf(mx[sj], pm[sj]);
        float sc = __expf(mx[sj] - mn);
        mx[sj] = mn;
        lsum[sj] *= sc;
#pragma unroll
        for (int ds = 0; ds < 4; ++ds)
#pragma unroll
          for (int r = 0; r < 4; ++r) o[sj][ds][r] *= sc;
      }
    }
#pragma unroll
    for (int sj = 0; sj < 2; ++sj) {
      float rs = 0.f;
#pragma unroll
      for (int kt = 0; kt < 4; ++kt) {
        bf16x4 pw;
#pragma unroll
        for (int r = 0; r < 4; ++r) {
          float e = __expf(sv[sj][kt][r] - mx[sj]);
          rs += e;
          pw[r] = (bf16)e;
        }
        *(bf16x4*)&Pl[w][sj][c * 68 + kt * 16 + 4 * g] = pw;
      }
      rs += __shfl_xor(rs, 16);
      rs += __shfl_xor(rs, 32);
      lsum[sj] += rs;
    }
    asm volatile("s_waitcnt lgkmcnt(0)" ::: "memory");
    __builtin_amdgcn_sched_barrier(0);

    __builtin_amdgcn_s_setprio(1);
#pragma unroll
    for (int ks = 0; ks < 2; ++ks) {
      bf16x8 pb0 = *(const bf16x8*)&Pl[w][0][c * 68 + ks * 32 + g * 8];
      bf16x8 pb1 = *(const bf16x8*)&Pl[w][1][c * 68 + ks * 32 + g * 8];
#pragma unroll
      for (int ds = 0; ds < 4; ++ds) {
        const char* vr = (const char*)&Vs[buf][(ds * 16 + c) * 64];
        bf16x8 va = *(const bf16x8*)(vr + ((ks * 64 + g * 16) ^ swz));
        o[0][ds] = __builtin_amdgcn_mfma_f32_16x16x32_bf16(va, pb0, o[0][ds], 0, 0, 0);
        o[1][ds] = __builtin_amdgcn_mfma_f32_16x16x32_bf16(va, pb1, o[1][ds], 0, 0, 0);
      }
    }
    __builtin_amdgcn_s_setprio(0);
    __builtin_amdgcn_s_barrier();  // raw: reads of buf done before next STAGE
    buf ^= 1;
  }

#pragma unroll
  for (int sj = 0; sj < 2; ++sj) {
    float inv = 1.f / lsum[sj];
    bf16* Orow = O + (long)(b * NS + q0 + sj * 16 + c) * ND + h * NDK;
#pragma unroll
    for (int ds = 0; ds < 4; ++ds) {
      bf16x4 ov;
#pragma unroll
      for (int r = 0; r < 4; ++r) ov[r] = (bf16)(o[sj][ds][r] * inv);
      *(bf16x4*)(Orow + ds * 16 + 4 * g) = ov;
    }
  }
#undef STAGE
}

extern "C" void kernel_launch(void* const* d_in, const int* in_sizes, int n_in,
                              void* d_out, int out_size, void* d_ws, size_t ws_size,
                              hipStream_t stream) {
  (void)in_sizes; (void)n_in; (void)out_size; (void)ws_size;
  const float* x = (const float*)d_in[0];
  const float* y = (const float*)d_in[1];
  const float* x_pos = (const float*)d_in[2];
  const float* y_pos = (const float*)d_in[3];

  char* ws = (char*)d_ws;
  const size_t MB = 1ull << 20;
  bf16* Wt[8];
  for (int i = 0; i < 8; ++i) Wt[i] = (bf16*)(ws + (size_t)i * 2 * MB);
  bf16* W1T = (bf16*)(ws + 16 * MB);
  bf16* W2T = (bf16*)(ws + 24 * MB);
  float* xres = (float*)(ws + 32 * MB);
  bf16* x2 = (bf16*)(ws + 64 * MB);
  bf16* qk = (bf16*)(ws + 80 * MB);
  bf16* y2 = (bf16*)(ws + 96 * MB);
  bf16* yk = (bf16*)(ws + 112 * MB);
  bf16* Qb = (bf16*)(ws + 128 * MB);
  bf16* Kb = (bf16*)(ws + 144 * MB);
  bf16* VTb = (bf16*)(ws + 176 * MB);
  bf16* Ob = (bf16*)(ws + 192 * MB);
  bf16* hb = (bf16*)(ws + 128 * MB);  // aliases Qb..VTb (free during FFN)

  dim3 tb(32, 8);
  WPtrs wp;
  for (int i = 0; i < 8; ++i) wp.w[i] = (const float*)d_in[4 + 2 * i];
  wconv8<<<dim3(32, 32, 8), tb, 0, stream>>>(wp, (bf16*)ws);
  wconv_t<<<dim3(128, 32), tb, 0, stream>>>((const float*)d_in[20], W1T, 1024, 4096);
  wconv_t<<<dim3(32, 128), tb, 0, stream>>>((const float*)d_in[22], W2T, 4096, 1024);

  const float* ln1g = (const float*)d_in[24]; const float* ln1b = (const float*)d_in[25];
  const float* ln2g = (const float*)d_in[26]; const float* ln2b = (const float*)d_in[27];
  const float* ln3g = (const float*)d_in[28]; const float* ln3b = (const float*)d_in[29];
  const float* ln4g = (const float*)d_in[30]; const float* ln4b = (const float*)d_in[31];

  dim3 gD(64, 8);      // 128^2 tiles
  dim3 gF1(32, 32);    // 256x128 tiles for FFN1

  // ---- self-attention ----
  ln_fused<<<8192, 256, 0, stream>>>(x, ln1g, ln1b, x_pos, x2, qk);
  gemm_bt<0><<<gD, 256, 0, stream>>>(qk, Wt[0], (const float*)d_in[5], nullptr, Qb, 8192, 1024, 1024);
  gemm_bt<0><<<gD, 256, 0, stream>>>(qk, Wt[1], (const float*)d_in[7], nullptr, Kb, 8192, 1024, 1024);
  gemm_bt<3><<<gD, 256, 0, stream>>>(x2, Wt[2], (const float*)d_in[9], nullptr, VTb, 8192, 1024, 1024);
  attn_fwd<<<512, 512, 0, stream>>>(Qb, Kb, VTb, Ob);
  gemm_bt<1><<<gD, 256, 0, stream>>>(Ob, Wt[3], (const float*)d_in[11], x, xres, 8192, 1024, 1024);

  // ---- cross-attention ----
  ln_fused<<<8192, 256, 0, stream>>>(xres, ln2g, ln2b, x_pos, nullptr, qk);
  ln_fused<<<8192, 256, 0, stream>>>(y, ln3g, ln3b, y_pos, y2, yk);
  gemm_bt<0><<<gD, 256, 0, stream>>>(qk, Wt[4], (const float*)d_in[13], nullptr, Qb, 8192, 1024, 1024);
  gemm_bt<0><<<gD, 256, 0, stream>>>(yk, Wt[5], (const float*)d_in[15], nullptr, Kb, 8192, 1024, 1024);
  gemm_bt<3><<<gD, 256, 0, stream>>>(y2, Wt[6], (const float*)d_in[17], nullptr, VTb, 8192, 1024, 1024);
  attn_fwd<<<512, 512, 0, stream>>>(Qb, Kb, VTb, Ob);
  gemm_bt<1><<<gD, 256, 0, stream>>>(Ob, Wt[7], (const float*)d_in[19], xres, xres, 8192, 1024, 1024);

  // ---- FFN ----
  ln_fused<<<8192, 256, 0, stream>>>(xres, ln4g, ln4b, nullptr, x2, nullptr);
  gemm_bt8<2><<<gF1, 512, 0, stream>>>(x2, W1T, (const float*)d_in[21], nullptr, hb, 8192, 4096, 1024);
  gemm_bt<1><<<gD, 256, 0, stream>>>(hb, W2T, (const float*)d_in[23], xres, (float*)d_out, 8192, 1024, 4096);
}